// Round 11
// baseline (1494.371 us; speedup 1.0000x reference)
//
#include <hip/hip_runtime.h>

#define CC 256
#define HH 256
#define WW 256
#define HWV 65536
#define NN 4096
#define CG 16        // channels (planes) per staged-gather block
#define SROWS 18     // staged rows: 16-row band + 1 above + 1 below
#define SSTRIDE 260  // padded LDS row stride (words): rotates banks by 4/row

using u64 = unsigned long long;
using u32 = unsigned int;

__device__ __forceinline__ u32 lbound(const u32* __restrict__ a, u32 n, u32 key) {
    u32 lo = 0, hi = n;
    while (lo < hi) { u32 mid = (lo + hi) >> 1; if (a[mid] < key) lo = mid + 1; else hi = mid; }
    return lo;
}

// ---------------------------------------------------------------------------
// K1: 48-bit sortable keys: (monotone(float) << 16) | (0xFFFF - pix).
// Distinct per pixel; descending key order == lax.top_k order.
__global__ void build_keys_k(const float* __restrict__ pm, const int* __restrict__ em,
                             u64* __restrict__ keys) {
    int i = blockIdx.x * blockDim.x + threadIdx.x;   // b*65536 + pix
    float f = (em[i] == 1) ? -fabsf(pm[i]) : -1e30f;
    u32 u = __float_as_uint(f);
    u32 k = (u & 0x80000000u) ? ~u : (u | 0x80000000u);
    u32 pix = (u32)i & 0xFFFFu;
    keys[i] = ((u64)k << 16) | (u64)(0xFFFFu - pix);
}

// ---------------------------------------------------------------------------
// K2: blocks 0-7 = per-batch exact top-k: 4x12-bit radix select + ONE desc
// bitonic (ranks) + bitmap/popcount spatial emit. DIRECT=1: write coords/idx
// outputs right here. blocks 8-15 = row counting-sort of point_coords.
template<int DIRECT>
__global__ __launch_bounds__(1024) void topk_sortpc_k(const u64* __restrict__ keys,
                                                      const float* __restrict__ pc,
                                                      u32* __restrict__ stash,
                                                      u32* __restrict__ pixSorted,
                                                      u32* __restrict__ pcSorted,
                                                      float* __restrict__ outCoord,
                                                      float* __restrict__ outIdx) {
    __shared__ u64 sel[NN];      // 32 KB (phase1 aliases first 16KB as hist[4096])
    __shared__ u64 bm[1024];     // 8 KB bitmap / type-B: u32 counters
    __shared__ u32 wp[1024];     // 4 KB word-prefix / type-B: hist256
    __shared__ u32 s_digit, s_rem, s_cnt;
    const int t = threadIdx.x;
    if (blockIdx.x < 8) {
        const int b = blockIdx.x;
        const u64* kb = keys + (size_t)b * HWV;
        u32* hist = (u32*)sel;   // 4096 bins
        u64 prefix = 0ULL;
        u32 remaining = NN;
        for (int r = 0; r < 4; ++r) {
            int shift = 36 - 12 * r;
            #pragma unroll
            for (int q = 0; q < 4; ++q) hist[t + q * 1024] = 0u;
            __syncthreads();
            for (int i = t; i < HWV; i += 1024) {
                u64 K = kb[i];
                if ((K >> (shift + 12)) == prefix)
                    atomicAdd(&hist[(u32)((K >> shift) & 0xFFFULL)], 1u);
            }
            __syncthreads();
            // in-place suffix sum over 4096 bins
            for (int off = 1; off < 4096; off <<= 1) {
                u32 v[4];
                #pragma unroll
                for (int q = 0; q < 4; ++q) {
                    int i = t + q * 1024;
                    v[q] = hist[i];
                    if (i + off < 4096) v[q] += hist[i + off];
                }
                __syncthreads();
                #pragma unroll
                for (int q = 0; q < 4; ++q) hist[t + q * 1024] = v[q];
                __syncthreads();
            }
            #pragma unroll
            for (int q = 0; q < 4; ++q) {
                int d = t + q * 1024;
                u32 ge = hist[d];
                u32 gt = (d < 4095) ? hist[d + 1] : 0u;
                if (ge >= remaining && gt < remaining) { s_digit = (u32)d; s_rem = remaining - gt; }
            }
            __syncthreads();
            prefix = (prefix << 12) | (u64)s_digit;
            remaining = s_rem;
            __syncthreads();
        }
        // compaction: exactly 4096 keys satisfy K >= prefix (keys distinct)
        if (t == 0) s_cnt = 0u;
        __syncthreads();
        for (int i = t; i < HWV; i += 1024) {
            u64 K = kb[i];
            if (K >= prefix) { u32 p = atomicAdd(&s_cnt, 1u); sel[p] = K; }
        }
        __syncthreads();
        // descending bitonic sort (ranks; desc value, asc pixel on ties)
        for (int k = 2; k <= NN; k <<= 1) {
            for (int j = k >> 1; j > 0; j >>= 1) {
                for (int i = t; i < NN; i += 1024) {
                    int l = i ^ j;
                    if (l > i) {
                        u64 a = sel[i], c = sel[l];
                        bool asc = ((i & k) == 0);
                        if ((a < c) == asc) { sel[i] = c; sel[l] = a; }
                    }
                }
                __syncthreads();
            }
        }
        // rank-order outputs + bitmap of selected pixels
        bm[t] = 0ULL;
        __syncthreads();
        #pragma unroll
        for (int q = 0; q < 4; ++q) {
            int r = t + q * 1024;
            u32 pix = 0xFFFFu - (u32)(sel[r] & 0xFFFFULL);
            if (DIRECT) {
                u32 yi = pix >> 8, xi = pix & 255u;
                outCoord[((size_t)b * NN + r) * 2 + 0] = (float)yi / 255.0f;
                outCoord[((size_t)b * NN + r) * 2 + 1] = (float)xi / 255.0f;
                outIdx[b * NN + r] = (float)pix;   // exact: pix < 2^24
            } else {
                stash[b * NN + r] = pix;
            }
            atomicOr(&bm[pix >> 6], 1ULL << (pix & 63));
        }
        __syncthreads();
        wp[t] = (u32)__popcll(bm[t]);
        __syncthreads();
        for (int off = 1; off < 1024; off <<= 1) {   // inclusive scan
            u32 v = wp[t];
            if (t >= off) v += wp[t - off];
            __syncthreads();
            wp[t] = v;
            __syncthreads();
        }
        // emit spatial order: pos = #selected pixels < pix (exact, == asc sort)
        #pragma unroll
        for (int q = 0; q < 4; ++q) {
            int r = t + q * 1024;
            u32 pix = 0xFFFFu - (u32)(sel[r] & 0xFFFFULL);
            int w = (int)(pix >> 6);
            u32 pos = wp[w] - (u32)__popcll(bm[w])
                    + (u32)__popcll(bm[w] & ((1ULL << (pix & 63)) - 1ULL));
            pixSorted[b * NN + pos] = (pix << 12) | (u32)r;
        }
    } else {
        // row counting-sort of pc (any within-row order is locality-equivalent)
        const int b = blockIdx.x - 8;
        u32* cellArr = (u32*)sel;    // 4096 u32
        u32* hist256 = wp;           // 256 bins
        u32* cnt     = (u32*)bm;     // 256 running counters
        if (t < 256) { hist256[t] = 0u; cnt[t] = 0u; }
        __syncthreads();
        for (int n = t; n < NN; n += 1024) {
            float gx = pc[((size_t)b * NN + n) * 2 + 0];
            float gy = pc[((size_t)b * NN + n) * 2 + 1];
            float fx = gx * 256.0f - 0.5f;
            float fy = gy * 256.0f - 0.5f;
            int x0 = (int)floorf(fx), y0 = (int)floorf(fy);
            int xc = min(max(x0, 0), 255), yc = min(max(y0, 0), 255);
            cellArr[n] = ((u32)(yc * 256 + xc) << 12) | (u32)n;
            atomicAdd(&hist256[yc], 1u);
        }
        __syncthreads();
        for (int off = 1; off < 256; off <<= 1) {    // inclusive scan over 256
            u32 v = 0;
            if (t < 256) { v = hist256[t]; if (t >= off) v += hist256[t - off]; }
            __syncthreads();
            if (t < 256) hist256[t] = v;
            __syncthreads();
        }
        for (int n = t; n < NN; n += 1024) {
            u32 pk = cellArr[n];
            u32 yc = pk >> 20;
            u32 base = (yc > 0) ? hist256[yc - 1] : 0u;
            u32 pos = base + atomicAdd(&cnt[yc], 1u);
            pcSorted[b * NN + pos] = pk;
        }
    }
}

// ---------------------------------------------------------------------------
// Staging helpers: 18-row band slice, coalesced float4 loads, padded LDS rows.
__device__ __forceinline__ void stage_load(const float* __restrict__ plane, int rStart,
                                           float4 (&stg)[5], int t) {
    #pragma unroll
    for (int u = 0; u < 5; ++u) {
        int idx = t + u * 256;
        if (idx < SROWS * 64) {
            int row = idx >> 6, c4 = idx & 63;
            int gr = min(max(rStart + row, 0), HH - 1);   // clamp: OOB rows unused
            stg[u] = *(const float4*)(plane + gr * WW + c4 * 4);
        }
    }
}
__device__ __forceinline__ void stage_store(float* __restrict__ dst,
                                            const float4 (&stg)[5], int t) {
    #pragma unroll
    for (int u = 0; u < 5; ++u) {
        int idx = t + u * 256;
        if (idx < SROWS * 64) {
            int row = idx >> 6, c4 = idx & 63;
            *(float4*)(dst + row * SSTRIDE + c4 * 4) = stg[u];
        }
    }
}

// ---------------------------------------------------------------------------
// K3: LDS-staged band-fused gather ("round 8 done right").
// Block = (band of 16 rows, 16-plane group, b). Double-buffered band staging,
// 1 barrier/plane, ~90 VGPR, 37.4 KB LDS -> 4 blocks/CU. Both point sets tap
// from LDS; outputs written 64B/point from registers.
__global__ __launch_bounds__(256, 4) void staged_gather_k(const float* __restrict__ fm,
                                                          const float* __restrict__ pc,
                                                          const u32* __restrict__ pixSorted,
                                                          const u32* __restrict__ pcSorted,
                                                          float* __restrict__ outLp,
                                                          float* __restrict__ outS) {
    __shared__ float smA[SROWS * SSTRIDE];
    __shared__ float smB[SROWS * SSTRIDE];
    const int b = blockIdx.z, c0 = blockIdx.y * CG, band = blockIdx.x;
    const int t = threadIdx.x;
    const int rStart = band * 16 - 1;
    const u32 keyLo = (u32)band << 24, keyHi = (u32)(band + 1) << 24;
    const u32* aL = pixSorted + b * NN;
    const u32* aS = pcSorted + b * NN;
    u32 loL = lbound(aL, NN, keyLo), cL = lbound(aL, NN, keyHi) - loL;
    u32 loS = lbound(aS, NN, keyLo), cS = lbound(aS, NN, keyHi) - loS;
    u32 cMax = cL > cS ? cL : cS;
    u32 chunks = (cMax + 255) >> 8;
    const float* planes = fm + ((size_t)b * CC + c0) * HWV;
    const float* pcb = pc + (size_t)b * NN * 2;

    for (u32 ch = 0; ch < chunks; ++ch) {
        // ---- decode L point (weights 0 if none) ----
        int lo0 = 0, lo1 = 0, lo2 = 0; u32 rank = 0; int hasL = 0;
        float w8[8]; float wr2 = 0.0f, invc = 0.0f;
        #pragma unroll
        for (int i = 0; i < 8; ++i) w8[i] = 0.0f;
        {
            u32 jl = ch * 256 + (u32)t;
            if (jl < cL) {
                hasL = 1;
                u32 packed = aL[loL + jl];
                u32 pix = packed >> 12;
                rank = packed & 0xFFFu;
                int yi = (int)(pix >> 8), xi = (int)(pix & 255u);
                // replicate the reference float pipeline exactly
                float cy = (float)yi / 255.0f, cx = (float)xi / 255.0f;
                int x = (int)(cx * 255.0f), y = (int)(cy * 255.0f);
                int x_min = max(x - 1, 0), x_max = min(x + 2, WW);
                int y_min = max(y - 1, 0), y_max = min(y + 2, HH);
                int base = min(x_min & ~3, WW - 8);
                #pragma unroll
                for (int i = 0; i < 8; ++i)
                    w8[i] = (base + i >= x_min && base + i < x_max) ? 1.0f : 0.0f;
                wr2 = (y_min + 2 < y_max) ? 1.0f : 0.0f;
                lo0 = (y_min - rStart) * SSTRIDE + base;
                lo1 = lo0 + SSTRIDE;
                lo2 = (min(y_min + 2, HH - 1) - rStart) * SSTRIDE + base;
                invc = 1.0f / (float)((x_max - x_min) * (y_max - y_min));
            }
        }
        // ---- decode S point ----
        int so0 = 0, so1 = 0; u32 sn = 0; int hasS = 0;
        float wv0 = 0.0f, wv1 = 0.0f, wr0 = 0.0f, wr1 = 0.0f;
        {
            u32 js = ch * 256 + (u32)t;
            if (js < cS) {
                hasS = 1;
                u32 packed = aS[loS + js];
                sn = packed & 0xFFFu;
                float gx = pcb[2 * sn + 0], gy = pcb[2 * sn + 1];
                float fx = gx * 256.0f - 0.5f;   // power-of-2 mul: exact
                float fy = gy * 256.0f - 0.5f;
                float fx0 = floorf(fx), fy0 = floorf(fy);
                int x0 = (int)fx0, y0 = (int)fy0;
                float wx = fx - fx0, wy = fy - fy0;
                int xb = min(max(x0, 0), WW - 2);
                if (x0 < 0)            { wv0 = wx;        wv1 = 0.0f; }
                else if (x0 >= WW - 1) { wv0 = 0.0f;      wv1 = 1.0f - wx; }
                else                   { wv0 = 1.0f - wx; wv1 = wx; }
                wr0 = (y0 >= 0)     ? (1.0f - wy) : 0.0f;
                wr1 = (y0 + 1 < HH) ? wy          : 0.0f;
                int yc0 = min(max(y0, 0), HH - 1);
                int yc1 = min(max(y0 + 1, 0), HH - 1);
                so0 = (yc0 - rStart) * SSTRIDE + xb;
                so1 = (yc1 - rStart) * SSTRIDE + xb;
            }
        }
        float vL[CG], vS[CG];
        // ---- prologue: stage plane 0 ----
        {
            float4 stg[5];
            stage_load(planes, rStart, stg, t);
            stage_store(smA, stg, t);
        }
        __syncthreads();
        // ---- plane loop: double-buffered, 1 barrier/plane ----
        #pragma unroll
        for (int j = 0; j < CG; ++j) {
            const float* cur = (j & 1) ? smB : smA;
            float* nxt = (j & 1) ? smA : smB;
            float4 stg[5];
            if (j + 1 < CG) stage_load(planes + (size_t)(j + 1) * HWV, rStart, stg, t);
            // L taps: 3 rows x 2 aligned float4 LDS reads
            {
                float4 a0 = *(const float4*)(cur + lo0);
                float4 b0 = *(const float4*)(cur + lo0 + 4);
                float4 a1 = *(const float4*)(cur + lo1);
                float4 b1 = *(const float4*)(cur + lo1 + 4);
                float4 a2 = *(const float4*)(cur + lo2);
                float4 b2 = *(const float4*)(cur + lo2 + 4);
                float s0 = a0.x * w8[0] + a0.y * w8[1] + a0.z * w8[2] + a0.w * w8[3]
                         + b0.x * w8[4] + b0.y * w8[5] + b0.z * w8[6] + b0.w * w8[7];
                float s1 = a1.x * w8[0] + a1.y * w8[1] + a1.z * w8[2] + a1.w * w8[3]
                         + b1.x * w8[4] + b1.y * w8[5] + b1.z * w8[6] + b1.w * w8[7];
                float s2 = a2.x * w8[0] + a2.y * w8[1] + a2.z * w8[2] + a2.w * w8[3]
                         + b2.x * w8[4] + b2.y * w8[5] + b2.z * w8[6] + b2.w * w8[7];
                vL[j] = (s0 + s1 + wr2 * s2) * invc;
            }
            // S taps: 2 rows x 2 scalar LDS reads
            vS[j] = wr0 * (cur[so0] * wv0 + cur[so0 + 1] * wv1)
                  + wr1 * (cur[so1] * wv0 + cur[so1 + 1] * wv1);
            if (j + 1 < CG) stage_store(nxt, stg, t);
            __syncthreads();
        }
        // ---- write out: 64B per point, full cache lines ----
        if (hasL) {
            float4* d = (float4*)(outLp + ((size_t)b * NN + rank) * CC + c0);
            #pragma unroll
            for (int u = 0; u < 4; ++u)
                d[u] = make_float4(vL[4 * u], vL[4 * u + 1], vL[4 * u + 2], vL[4 * u + 3]);
        }
        if (hasS) {
            float4* d = (float4*)(outS + ((size_t)b * NN + sn) * CC + c0);
            #pragma unroll
            for (int u = 0; u < 4; ++u)
                d[u] = make_float4(vS[4 * u], vS[4 * u + 1], vS[4 * u + 2], vS[4 * u + 3]);
        }
    }
}

// ---------------------------------------------------------------------------
// K3b (fallback path only, no-ws): round-10 merged/split gather.
template<int MODE>
__global__ __launch_bounds__(256, 4) void gather_k(const float* __restrict__ fm,
                                                   const float* __restrict__ pc,
                                                   const u32* __restrict__ pixSorted,
                                                   const u32* __restrict__ pcSorted,
                                                   float* __restrict__ outLp,
                                                   float* __restrict__ outS) {
    __shared__ float tile[256][33];
    __shared__ u32 pidx[256];
    const int b = blockIdx.z, j0 = blockIdx.x * 256, t = threadIdx.x;
    bool doL; int c0;
    if (MODE == 1) { doL = true; c0 = blockIdx.y * 32; }
    else { doL = false; c0 = blockIdx.y * 32; }
    const float* planes = fm + ((size_t)b * CC + c0) * HWV;
    if (doL) {
        u32 packed = pixSorted[b * NN + j0 + t];
        u32 pix = packed >> 12;
        pidx[t] = packed & 0xFFFu;
        int yi = (int)(pix >> 8), xi = (int)(pix & 255u);
        float cy = (float)yi / 255.0f, cx = (float)xi / 255.0f;
        int x = (int)(cx * 255.0f), y = (int)(cy * 255.0f);
        int x_min = max(x - 1, 0), x_max = min(x + 2, WW);
        int y_min = max(y - 1, 0), y_max = min(y + 2, HH);
        int base = min(x_min & ~3, WW - 8);
        float w8[8];
        #pragma unroll
        for (int i = 0; i < 8; ++i)
            w8[i] = (base + i >= x_min && base + i < x_max) ? 1.0f : 0.0f;
        float wr2 = (y_min + 2 < y_max) ? 1.0f : 0.0f;
        int o0 = y_min * WW + base, o1 = o0 + WW;
        int o2 = min(y_min + 2, HH - 1) * WW + base;
        float invc = 1.0f / (float)((x_max - x_min) * (y_max - y_min));
        #pragma unroll 2
        for (int j = 0; j < 32; ++j) {
            const float* p = planes + (size_t)j * HWV;
            float4 a0 = *(const float4*)(p + o0), b0 = *(const float4*)(p + o0 + 4);
            float4 a1 = *(const float4*)(p + o1), b1 = *(const float4*)(p + o1 + 4);
            float4 a2 = *(const float4*)(p + o2), b2 = *(const float4*)(p + o2 + 4);
            float s0 = a0.x * w8[0] + a0.y * w8[1] + a0.z * w8[2] + a0.w * w8[3]
                     + b0.x * w8[4] + b0.y * w8[5] + b0.z * w8[6] + b0.w * w8[7];
            float s1 = a1.x * w8[0] + a1.y * w8[1] + a1.z * w8[2] + a1.w * w8[3]
                     + b1.x * w8[4] + b1.y * w8[5] + b1.z * w8[6] + b1.w * w8[7];
            float s2 = a2.x * w8[0] + a2.y * w8[1] + a2.z * w8[2] + a2.w * w8[3]
                     + b2.x * w8[4] + b2.y * w8[5] + b2.z * w8[6] + b2.w * w8[7];
            tile[t][j] = (s0 + s1 + wr2 * s2) * invc;
        }
        __syncthreads();
        for (int idx = t; idx < 8192; idx += 256) {
            int p = idx >> 5, k = idx & 31;
            outLp[((size_t)b * NN + pidx[p]) * CC + c0 + k] = tile[p][k];
        }
    } else {
        int n = (int)(pcSorted[b * NN + j0 + t] & 0xFFFu);
        pidx[t] = (u32)n;
        float gx = pc[((size_t)b * NN + n) * 2 + 0];
        float gy = pc[((size_t)b * NN + n) * 2 + 1];
        float fx = gx * 256.0f - 0.5f, fy = gy * 256.0f - 0.5f;
        float fx0 = floorf(fx), fy0 = floorf(fy);
        int x0 = (int)fx0, y0 = (int)fy0;
        float wx = fx - fx0, wy = fy - fy0;
        int xb = min(max(x0, 0), WW - 2);
        float wv0, wv1;
        if (x0 < 0)            { wv0 = wx;        wv1 = 0.0f; }
        else if (x0 >= WW - 1) { wv0 = 0.0f;      wv1 = 1.0f - wx; }
        else                   { wv0 = 1.0f - wx; wv1 = wx; }
        float wr0 = (y0 >= 0)     ? (1.0f - wy) : 0.0f;
        float wr1 = (y0 + 1 < HH) ? wy          : 0.0f;
        int yc0 = min(max(y0, 0), HH - 1), yc1 = min(max(y0 + 1, 0), HH - 1);
        int o0 = yc0 * WW + xb, o1 = yc1 * WW + xb;
        #pragma unroll 4
        for (int j = 0; j < 32; ++j) {
            const float* p = planes + (size_t)j * HWV;
            tile[t][j] = wr0 * (p[o0] * wv0 + p[o0 + 1] * wv1)
                       + wr1 * (p[o1] * wv0 + p[o1 + 1] * wv1);
        }
        __syncthreads();
        for (int idx = t; idx < 8192; idx += 256) {
            int p = idx >> 5, k = idx & 31;
            outS[((size_t)b * NN + pidx[p]) * CC + c0 + k] = tile[p][k];
        }
    }
}

// ---------------------------------------------------------------------------
// K4: plain tile transpose outLp[b][r][c] -> outL[b][c][r].
__global__ __launch_bounds__(256) void transpose_k(const float* __restrict__ outLp,
                                                   float* __restrict__ outL) {
    __shared__ float tile[256][33];
    const int b = blockIdx.z, c0 = blockIdx.y * 32, r0 = blockIdx.x * 256;
    const int t = threadIdx.x;
    for (int idx = t; idx < 8192; idx += 256) {
        int p = idx >> 5, k = idx & 31;
        tile[p][k] = outLp[((size_t)b * NN + r0 + p) * CC + c0 + k];
    }
    __syncthreads();
    for (int idx = t; idx < 8192; idx += 256) {
        int cl = idx >> 8, col = idx & 255;
        outL[((size_t)b * CC + c0 + cl) * NN + r0 + col] = tile[col][cl];
    }
}

// ---------------------------------------------------------------------------
// K5 (fallback path only): coords + idx from the rank-order stash.
__global__ void emit_k(const u32* __restrict__ stash, float* __restrict__ outCoord,
                       float* __restrict__ outIdx) {
    int i = blockIdx.x * blockDim.x + threadIdx.x;   // 0..32767
    u32 p = stash[i];
    u32 yi = p >> 8, xi = p & 255u;
    outCoord[(size_t)i * 2 + 0] = (float)yi / 255.0f;
    outCoord[(size_t)i * 2 + 1] = (float)xi / 255.0f;
    outIdx[i] = (float)p;   // exact: p < 2^24
}

extern "C" void kernel_launch(void* const* d_in, const int* in_sizes, int n_in,
                              void* d_out, int out_size, void* d_ws, size_t ws_size,
                              hipStream_t stream) {
    const float* fm = (const float*)d_in[0];   // (8,256,256,256) f32
    const float* pm = (const float*)d_in[1];   // (8,1,256,256) f32
    const int*   em = (const int*)d_in[2];     // (8,256,256) i32
    const float* pc = (const float*)d_in[3];   // (8,4096,2) f32
    (void)in_sizes; (void)n_in; (void)out_size;

    float* out      = (float*)d_out;
    float* outL     = out;                         // local_feats (8,256,4096)
    float* outS     = out + (size_t)8388608;       // sampled     (8,4096,256)
    float* outCoord = out + (size_t)16777216;      // coords      (8,4096,2)
    float* outIdx   = out + (size_t)16842752;      // idx         (8,4096)

    const size_t need_ws = (size_t)40 * 1024 * 1024;
    bool ws_ok = ws_size >= need_ws;

    u64* keys; u32 *stash, *pixSorted, *pcSorted; float* outLp;
    if (ws_ok) {
        char* w = (char*)d_ws;
        keys      = (u64*)w;                                // 4 MB
        stash     = (u32*)(w + (size_t)4  * 1024 * 1024);   // (unused, DIRECT)
        pixSorted = (u32*)(w + (size_t)4300 * 1024);        // 128 KB
        pcSorted  = (u32*)(w + (size_t)4600 * 1024);        // 128 KB
        outLp     = (float*)(w + (size_t)5 * 1024 * 1024);  // 33.5 MB
    } else {
        // alias scheme: keys/outLp in seg1 (final writer = gather<2>),
        // pixSorted/pcSorted in seg2 (final writer = emit), stash in seg3.
        keys      = (u64*)outS;
        stash     = (u32*)outIdx;
        pixSorted = (u32*)outCoord;
        pcSorted  = pixSorted + 32768;
        outLp     = outS;
    }

    hipLaunchKernelGGL(build_keys_k, dim3(2048), dim3(256), 0, stream, pm, em, keys);
    if (ws_ok) {
        hipLaunchKernelGGL((topk_sortpc_k<1>), dim3(16), dim3(1024), 0, stream,
                           keys, pc, stash, pixSorted, pcSorted, outCoord, outIdx);
        hipLaunchKernelGGL(staged_gather_k, dim3(16, CC / CG, 8), dim3(256), 0, stream,
                           fm, pc, pixSorted, pcSorted, outLp, outS);
        hipLaunchKernelGGL(transpose_k, dim3(16, 8, 8), dim3(256), 0, stream, outLp, outL);
    } else {
        hipLaunchKernelGGL((topk_sortpc_k<0>), dim3(16), dim3(1024), 0, stream,
                           keys, pc, stash, pixSorted, pcSorted, outCoord, outIdx);
        hipLaunchKernelGGL((gather_k<1>), dim3(16, 8, 8), dim3(256), 0, stream,
                           fm, pc, pixSorted, pcSorted, outLp, outS);
        hipLaunchKernelGGL(transpose_k, dim3(16, 8, 8), dim3(256), 0, stream, outLp, outL);
        hipLaunchKernelGGL((gather_k<2>), dim3(16, 8, 8), dim3(256), 0, stream,
                           fm, pc, pixSorted, pcSorted, outS, outS);
        hipLaunchKernelGGL(emit_k, dim3(128), dim3(256), 0, stream, stash, outCoord, outIdx);
    }
}

// Round 12
// 593.946 us; speedup vs baseline: 2.5160x; 2.5160x over previous
//
#include <hip/hip_runtime.h>

#define CC 256
#define HH 256
#define WW 256
#define HWV 65536
#define NN 4096
#define CG 8         // channels (planes) per staged-gather block
#define SROWS 18     // staged rows: 16-row band + 1 above + 1 below
#define SSTRIDE 260  // padded LDS row stride (words)

using u64 = unsigned long long;
using u32 = unsigned int;

__device__ __forceinline__ u32 lbound(const u32* __restrict__ a, u32 n, u32 key) {
    u32 lo = 0, hi = n;
    while (lo < hi) { u32 mid = (lo + hi) >> 1; if (a[mid] < key) lo = mid + 1; else hi = mid; }
    return lo;
}

// ---------------------------------------------------------------------------
// K1: 48-bit sortable keys: (monotone(float) << 16) | (0xFFFF - pix).
__global__ void build_keys_k(const float* __restrict__ pm, const int* __restrict__ em,
                             u64* __restrict__ keys) {
    int i = blockIdx.x * blockDim.x + threadIdx.x;   // b*65536 + pix
    float f = (em[i] == 1) ? -fabsf(pm[i]) : -1e30f;
    u32 u = __float_as_uint(f);
    u32 k = (u & 0x80000000u) ? ~u : (u | 0x80000000u);
    u32 pix = (u32)i & 0xFFFFu;
    keys[i] = ((u64)k << 16) | (u64)(0xFFFFu - pix);
}

// ---------------------------------------------------------------------------
// K2: blocks 0-7 = per-batch exact top-k: 4x12-bit radix select + ONE desc
// bitonic (ranks) + bitmap/popcount spatial emit. DIRECT=1: write coords/idx
// here. blocks 8-15 = row counting-sort of point_coords.
template<int DIRECT>
__global__ __launch_bounds__(1024) void topk_sortpc_k(const u64* __restrict__ keys,
                                                      const float* __restrict__ pc,
                                                      u32* __restrict__ stash,
                                                      u32* __restrict__ pixSorted,
                                                      u32* __restrict__ pcSorted,
                                                      float* __restrict__ outCoord,
                                                      float* __restrict__ outIdx) {
    __shared__ u64 sel[NN];
    __shared__ u64 bm[1024];
    __shared__ u32 wp[1024];
    __shared__ u32 s_digit, s_rem, s_cnt;
    const int t = threadIdx.x;
    if (blockIdx.x < 8) {
        const int b = blockIdx.x;
        const u64* kb = keys + (size_t)b * HWV;
        u32* hist = (u32*)sel;
        u64 prefix = 0ULL;
        u32 remaining = NN;
        for (int r = 0; r < 4; ++r) {
            int shift = 36 - 12 * r;
            #pragma unroll
            for (int q = 0; q < 4; ++q) hist[t + q * 1024] = 0u;
            __syncthreads();
            for (int i = t; i < HWV; i += 1024) {
                u64 K = kb[i];
                if ((K >> (shift + 12)) == prefix)
                    atomicAdd(&hist[(u32)((K >> shift) & 0xFFFULL)], 1u);
            }
            __syncthreads();
            for (int off = 1; off < 4096; off <<= 1) {   // suffix sums
                u32 v[4];
                #pragma unroll
                for (int q = 0; q < 4; ++q) {
                    int i = t + q * 1024;
                    v[q] = hist[i];
                    if (i + off < 4096) v[q] += hist[i + off];
                }
                __syncthreads();
                #pragma unroll
                for (int q = 0; q < 4; ++q) hist[t + q * 1024] = v[q];
                __syncthreads();
            }
            #pragma unroll
            for (int q = 0; q < 4; ++q) {
                int d = t + q * 1024;
                u32 ge = hist[d];
                u32 gt = (d < 4095) ? hist[d + 1] : 0u;
                if (ge >= remaining && gt < remaining) { s_digit = (u32)d; s_rem = remaining - gt; }
            }
            __syncthreads();
            prefix = (prefix << 12) | (u64)s_digit;
            remaining = s_rem;
            __syncthreads();
        }
        if (t == 0) s_cnt = 0u;
        __syncthreads();
        for (int i = t; i < HWV; i += 1024) {
            u64 K = kb[i];
            if (K >= prefix) { u32 p = atomicAdd(&s_cnt, 1u); sel[p] = K; }
        }
        __syncthreads();
        for (int k = 2; k <= NN; k <<= 1) {           // bitonic desc
            for (int j = k >> 1; j > 0; j >>= 1) {
                for (int i = t; i < NN; i += 1024) {
                    int l = i ^ j;
                    if (l > i) {
                        u64 a = sel[i], c = sel[l];
                        bool asc = ((i & k) == 0);
                        if ((a < c) == asc) { sel[i] = c; sel[l] = a; }
                    }
                }
                __syncthreads();
            }
        }
        bm[t] = 0ULL;
        __syncthreads();
        #pragma unroll
        for (int q = 0; q < 4; ++q) {
            int r = t + q * 1024;
            u32 pix = 0xFFFFu - (u32)(sel[r] & 0xFFFFULL);
            if (DIRECT) {
                u32 yi = pix >> 8, xi = pix & 255u;
                outCoord[((size_t)b * NN + r) * 2 + 0] = (float)yi / 255.0f;
                outCoord[((size_t)b * NN + r) * 2 + 1] = (float)xi / 255.0f;
                outIdx[b * NN + r] = (float)pix;   // exact: pix < 2^24
            } else {
                stash[b * NN + r] = pix;
            }
            atomicOr(&bm[pix >> 6], 1ULL << (pix & 63));
        }
        __syncthreads();
        wp[t] = (u32)__popcll(bm[t]);
        __syncthreads();
        for (int off = 1; off < 1024; off <<= 1) {   // inclusive scan
            u32 v = wp[t];
            if (t >= off) v += wp[t - off];
            __syncthreads();
            wp[t] = v;
            __syncthreads();
        }
        #pragma unroll
        for (int q = 0; q < 4; ++q) {
            int r = t + q * 1024;
            u32 pix = 0xFFFFu - (u32)(sel[r] & 0xFFFFULL);
            int w = (int)(pix >> 6);
            u32 pos = wp[w] - (u32)__popcll(bm[w])
                    + (u32)__popcll(bm[w] & ((1ULL << (pix & 63)) - 1ULL));
            pixSorted[b * NN + pos] = (pix << 12) | (u32)r;
        }
    } else {
        const int b = blockIdx.x - 8;
        u32* cellArr = (u32*)sel;
        u32* hist256 = wp;
        u32* cnt     = (u32*)bm;
        if (t < 256) { hist256[t] = 0u; cnt[t] = 0u; }
        __syncthreads();
        for (int n = t; n < NN; n += 1024) {
            float gx = pc[((size_t)b * NN + n) * 2 + 0];
            float gy = pc[((size_t)b * NN + n) * 2 + 1];
            float fx = gx * 256.0f - 0.5f;
            float fy = gy * 256.0f - 0.5f;
            int x0 = (int)floorf(fx), y0 = (int)floorf(fy);
            int xc = min(max(x0, 0), 255), yc = min(max(y0, 0), 255);
            cellArr[n] = ((u32)(yc * 256 + xc) << 12) | (u32)n;
            atomicAdd(&hist256[yc], 1u);
        }
        __syncthreads();
        for (int off = 1; off < 256; off <<= 1) {
            u32 v = 0;
            if (t < 256) { v = hist256[t]; if (t >= off) v += hist256[t - off]; }
            __syncthreads();
            if (t < 256) hist256[t] = v;
            __syncthreads();
        }
        for (int n = t; n < NN; n += 1024) {
            u32 pk = cellArr[n];
            u32 yc = pk >> 20;
            u32 base = (yc > 0) ? hist256[yc - 1] : 0u;
            u32 pos = base + atomicAdd(&cnt[yc], 1u);
            pcSorted[b * NN + pos] = pk;
        }
    }
}

// ---------------------------------------------------------------------------
// K3: LDS-staged band-fused gather, 512 threads, CG=8, single pass.
// Register budget by construction: vL[8]+vS[8]=16, stg 3xfloat4=12, decode
// ~25, misc ~30 -> ~85 VGPR under the 128 cap of __launch_bounds__(512,4).
__global__ __launch_bounds__(512, 4) void staged_gather512_k(const float* __restrict__ fm,
                                                             const float* __restrict__ pc,
                                                             const u32* __restrict__ pixSorted,
                                                             const u32* __restrict__ pcSorted,
                                                             float* __restrict__ outLp,
                                                             float* __restrict__ outS) {
    __shared__ float smA[SROWS * SSTRIDE];
    __shared__ float smB[SROWS * SSTRIDE];
    const int b = blockIdx.z, c0 = blockIdx.y * CG, band = blockIdx.x;
    const int t = threadIdx.x;
    const int rStart = band * 16 - 1;
    const u32 keyLo = (u32)band << 24, keyHi = (u32)(band + 1) << 24;
    const u32* aL = pixSorted + b * NN;
    const u32* aS = pcSorted + b * NN;
    u32 loL = lbound(aL, NN, keyLo), cL = lbound(aL, NN, keyHi) - loL;
    u32 loS = lbound(aS, NN, keyLo), cS = lbound(aS, NN, keyHi) - loS;
    const float* planes = fm + ((size_t)b * CC + c0) * HWV;
    const float* pcb = pc + (size_t)b * NN * 2;

    // ---- decode L point (weights 0 if none) ----
    int lo0 = 0, lo1 = 0, lo2 = 0; u32 rank = 0; int hasL = 0;
    float w8[8]; float wr2 = 0.0f, invc = 0.0f;
    #pragma unroll
    for (int i = 0; i < 8; ++i) w8[i] = 0.0f;
    if ((u32)t < cL) {
        hasL = 1;
        u32 packed = aL[loL + t];
        u32 pix = packed >> 12;
        rank = packed & 0xFFFu;
        int yi = (int)(pix >> 8), xi = (int)(pix & 255u);
        // replicate the reference float pipeline exactly (div, mul, trunc)
        float cy = (float)yi / 255.0f, cx = (float)xi / 255.0f;
        int x = (int)(cx * 255.0f), y = (int)(cy * 255.0f);
        int x_min = max(x - 1, 0), x_max = min(x + 2, WW);
        int y_min = max(y - 1, 0), y_max = min(y + 2, HH);
        int base = min(x_min & ~3, WW - 8);
        #pragma unroll
        for (int i = 0; i < 8; ++i)
            w8[i] = (base + i >= x_min && base + i < x_max) ? 1.0f : 0.0f;
        wr2 = (y_min + 2 < y_max) ? 1.0f : 0.0f;
        lo0 = (y_min - rStart) * SSTRIDE + base;
        lo1 = lo0 + SSTRIDE;
        lo2 = (min(y_min + 2, HH - 1) - rStart) * SSTRIDE + base;
        invc = 1.0f / (float)((x_max - x_min) * (y_max - y_min));
    }
    // ---- decode S point ----
    int so0 = 0, so1 = 0; u32 sn = 0; int hasS = 0;
    float wv0 = 0.0f, wv1 = 0.0f, wr0 = 0.0f, wr1 = 0.0f;
    if ((u32)t < cS) {
        hasS = 1;
        u32 packed = aS[loS + t];
        sn = packed & 0xFFFu;
        float gx = pcb[2 * sn + 0], gy = pcb[2 * sn + 1];
        float fx = gx * 256.0f - 0.5f;   // power-of-2 mul: exact
        float fy = gy * 256.0f - 0.5f;
        float fx0 = floorf(fx), fy0 = floorf(fy);
        int x0 = (int)fx0, y0 = (int)fy0;
        float wx = fx - fx0, wy = fy - fy0;
        int xb = min(max(x0, 0), WW - 2);
        if (x0 < 0)            { wv0 = wx;        wv1 = 0.0f; }
        else if (x0 >= WW - 1) { wv0 = 0.0f;      wv1 = 1.0f - wx; }
        else                   { wv0 = 1.0f - wx; wv1 = wx; }
        wr0 = (y0 >= 0)     ? (1.0f - wy) : 0.0f;
        wr1 = (y0 + 1 < HH) ? wy          : 0.0f;
        int yc0 = min(max(y0, 0), HH - 1);
        int yc1 = min(max(y0 + 1, 0), HH - 1);
        so0 = (yc0 - rStart) * SSTRIDE + xb;
        so1 = (yc1 - rStart) * SSTRIDE + xb;
    }

    float vL[CG], vS[CG];
    // ---- prologue: stage plane 0 into smA ----
    {
        #pragma unroll
        for (int u = 0; u < 3; ++u) {
            int idx = t + u * 512;
            if (idx < SROWS * 64) {
                int row = idx >> 6, c4 = idx & 63;
                int gr = min(max(rStart + row, 0), HH - 1);
                *(float4*)(smA + row * SSTRIDE + c4 * 4) =
                    *(const float4*)(planes + gr * WW + c4 * 4);
            }
        }
    }
    __syncthreads();
    // ---- plane loop: double-buffered, 1 barrier/plane ----
    #pragma unroll
    for (int j = 0; j < CG; ++j) {
        const float* cur = (j & 1) ? smB : smA;
        float* nxt = (j & 1) ? smA : smB;
        float4 g0, g1, g2;
        if (j + 1 < CG) {
            const float* np = planes + (size_t)(j + 1) * HWV;
            #pragma unroll
            for (int u = 0; u < 3; ++u) {
                int idx = t + u * 512;
                if (idx < SROWS * 64) {
                    int row = idx >> 6, c4 = idx & 63;
                    int gr = min(max(rStart + row, 0), HH - 1);
                    float4 v = *(const float4*)(np + gr * WW + c4 * 4);
                    if (u == 0) g0 = v; else if (u == 1) g1 = v; else g2 = v;
                }
            }
        }
        // L taps: 3 rows x 2 aligned float4 LDS reads
        {
            float4 a0 = *(const float4*)(cur + lo0);
            float4 b0 = *(const float4*)(cur + lo0 + 4);
            float4 a1 = *(const float4*)(cur + lo1);
            float4 b1 = *(const float4*)(cur + lo1 + 4);
            float4 a2 = *(const float4*)(cur + lo2);
            float4 b2 = *(const float4*)(cur + lo2 + 4);
            float s0 = a0.x * w8[0] + a0.y * w8[1] + a0.z * w8[2] + a0.w * w8[3]
                     + b0.x * w8[4] + b0.y * w8[5] + b0.z * w8[6] + b0.w * w8[7];
            float s1 = a1.x * w8[0] + a1.y * w8[1] + a1.z * w8[2] + a1.w * w8[3]
                     + b1.x * w8[4] + b1.y * w8[5] + b1.z * w8[6] + b1.w * w8[7];
            float s2 = a2.x * w8[0] + a2.y * w8[1] + a2.z * w8[2] + a2.w * w8[3]
                     + b2.x * w8[4] + b2.y * w8[5] + b2.z * w8[6] + b2.w * w8[7];
            vL[j] = (s0 + s1 + wr2 * s2) * invc;
        }
        // S taps: 2 rows x 2 scalar LDS reads
        vS[j] = wr0 * (cur[so0] * wv0 + cur[so0 + 1] * wv1)
              + wr1 * (cur[so1] * wv0 + cur[so1 + 1] * wv1);
        if (j + 1 < CG) {
            #pragma unroll
            for (int u = 0; u < 3; ++u) {
                int idx = t + u * 512;
                if (idx < SROWS * 64) {
                    int row = idx >> 6, c4 = idx & 63;
                    float4 v = (u == 0) ? g0 : (u == 1) ? g1 : g2;
                    *(float4*)(nxt + row * SSTRIDE + c4 * 4) = v;
                }
            }
        }
        __syncthreads();
    }
    // ---- writes: 32B per point ----
    if (hasL) {
        float4* d = (float4*)(outLp + ((size_t)b * NN + rank) * CC + c0);
        d[0] = make_float4(vL[0], vL[1], vL[2], vL[3]);
        d[1] = make_float4(vL[4], vL[5], vL[6], vL[7]);
    }
    if (hasS) {
        float4* d = (float4*)(outS + ((size_t)b * NN + sn) * CC + c0);
        d[0] = make_float4(vS[0], vS[1], vS[2], vS[3]);
        d[1] = make_float4(vS[4], vS[5], vS[6], vS[7]);
    }
    // ---- overflow epilogue (cL/cS > 512: statistically impossible, but safe):
    for (u32 jl = 512 + (u32)t; jl < cL; jl += 512) {
        u32 packed = aL[loL + jl];
        u32 pix = packed >> 12;
        u32 rk = packed & 0xFFFu;
        int yi = (int)(pix >> 8), xi = (int)(pix & 255u);
        float cy = (float)yi / 255.0f, cx = (float)xi / 255.0f;
        int x = (int)(cx * 255.0f), y = (int)(cy * 255.0f);
        int x_min = max(x - 1, 0), x_max = min(x + 2, WW);
        int y_min = max(y - 1, 0), y_max = min(y + 2, HH);
        float s = 0.0f; int cnt = 0;
        for (int yy = y_min; yy < y_max; ++yy)
            for (int xx = x_min; xx < x_max; ++xx) ++cnt;
        for (int j = 0; j < CG; ++j) {
            const float* p = planes + (size_t)j * HWV;
            s = 0.0f;
            for (int yy = y_min; yy < y_max; ++yy)
                for (int xx = x_min; xx < x_max; ++xx)
                    s += p[yy * WW + xx];
            outLp[((size_t)b * NN + rk) * CC + c0 + j] = s / (float)cnt;
        }
    }
    for (u32 js = 512 + (u32)t; js < cS; js += 512) {
        u32 packed = aS[loS + js];
        u32 n2 = packed & 0xFFFu;
        float gx = pcb[2 * n2 + 0], gy = pcb[2 * n2 + 1];
        float fx = gx * 256.0f - 0.5f, fy = gy * 256.0f - 0.5f;
        float fx0 = floorf(fx), fy0 = floorf(fy);
        int x0 = (int)fx0, y0 = (int)fy0;
        float wx = fx - fx0, wy = fy - fy0;
        int xb = min(max(x0, 0), WW - 2);
        float v0, v1, r0, r1;
        if (x0 < 0)            { v0 = wx;        v1 = 0.0f; }
        else if (x0 >= WW - 1) { v0 = 0.0f;      v1 = 1.0f - wx; }
        else                   { v0 = 1.0f - wx; v1 = wx; }
        r0 = (y0 >= 0)     ? (1.0f - wy) : 0.0f;
        r1 = (y0 + 1 < HH) ? wy          : 0.0f;
        int yc0 = min(max(y0, 0), HH - 1), yc1 = min(max(y0 + 1, 0), HH - 1);
        int o0 = yc0 * WW + xb, o1 = yc1 * WW + xb;
        for (int j = 0; j < CG; ++j) {
            const float* p = planes + (size_t)j * HWV;
            outS[((size_t)b * NN + n2) * CC + c0 + j] =
                r0 * (p[o0] * v0 + p[o0 + 1] * v1) + r1 * (p[o1] * v0 + p[o1 + 1] * v1);
        }
    }
}

// ---------------------------------------------------------------------------
// K3b (fallback, no-ws): round-10 merged/split gather.
template<int MODE>
__global__ __launch_bounds__(256, 4) void gather_k(const float* __restrict__ fm,
                                                   const float* __restrict__ pc,
                                                   const u32* __restrict__ pixSorted,
                                                   const u32* __restrict__ pcSorted,
                                                   float* __restrict__ outLp,
                                                   float* __restrict__ outS) {
    __shared__ float tile[256][33];
    __shared__ u32 pidx[256];
    const int b = blockIdx.z, j0 = blockIdx.x * 256, t = threadIdx.x;
    bool doL; int c0;
    if (MODE == 1) { doL = true; c0 = blockIdx.y * 32; }
    else { doL = false; c0 = blockIdx.y * 32; }
    const float* planes = fm + ((size_t)b * CC + c0) * HWV;
    if (doL) {
        u32 packed = pixSorted[b * NN + j0 + t];
        u32 pix = packed >> 12;
        pidx[t] = packed & 0xFFFu;
        int yi = (int)(pix >> 8), xi = (int)(pix & 255u);
        float cy = (float)yi / 255.0f, cx = (float)xi / 255.0f;
        int x = (int)(cx * 255.0f), y = (int)(cy * 255.0f);
        int x_min = max(x - 1, 0), x_max = min(x + 2, WW);
        int y_min = max(y - 1, 0), y_max = min(y + 2, HH);
        int base = min(x_min & ~3, WW - 8);
        float w8[8];
        #pragma unroll
        for (int i = 0; i < 8; ++i)
            w8[i] = (base + i >= x_min && base + i < x_max) ? 1.0f : 0.0f;
        float wr2 = (y_min + 2 < y_max) ? 1.0f : 0.0f;
        int o0 = y_min * WW + base, o1 = o0 + WW;
        int o2 = min(y_min + 2, HH - 1) * WW + base;
        float invc = 1.0f / (float)((x_max - x_min) * (y_max - y_min));
        #pragma unroll 2
        for (int j = 0; j < 32; ++j) {
            const float* p = planes + (size_t)j * HWV;
            float4 a0 = *(const float4*)(p + o0), b0 = *(const float4*)(p + o0 + 4);
            float4 a1 = *(const float4*)(p + o1), b1 = *(const float4*)(p + o1 + 4);
            float4 a2 = *(const float4*)(p + o2), b2 = *(const float4*)(p + o2 + 4);
            float s0 = a0.x * w8[0] + a0.y * w8[1] + a0.z * w8[2] + a0.w * w8[3]
                     + b0.x * w8[4] + b0.y * w8[5] + b0.z * w8[6] + b0.w * w8[7];
            float s1 = a1.x * w8[0] + a1.y * w8[1] + a1.z * w8[2] + a1.w * w8[3]
                     + b1.x * w8[4] + b1.y * w8[5] + b1.z * w8[6] + b1.w * w8[7];
            float s2 = a2.x * w8[0] + a2.y * w8[1] + a2.z * w8[2] + a2.w * w8[3]
                     + b2.x * w8[4] + b2.y * w8[5] + b2.z * w8[6] + b2.w * w8[7];
            tile[t][j] = (s0 + s1 + wr2 * s2) * invc;
        }
        __syncthreads();
        for (int idx = t; idx < 8192; idx += 256) {
            int p = idx >> 5, k = idx & 31;
            outLp[((size_t)b * NN + pidx[p]) * CC + c0 + k] = tile[p][k];
        }
    } else {
        int n = (int)(pcSorted[b * NN + j0 + t] & 0xFFFu);
        pidx[t] = (u32)n;
        float gx = pc[((size_t)b * NN + n) * 2 + 0];
        float gy = pc[((size_t)b * NN + n) * 2 + 1];
        float fx = gx * 256.0f - 0.5f, fy = gy * 256.0f - 0.5f;
        float fx0 = floorf(fx), fy0 = floorf(fy);
        int x0 = (int)fx0, y0 = (int)fy0;
        float wx = fx - fx0, wy = fy - fy0;
        int xb = min(max(x0, 0), WW - 2);
        float wv0, wv1;
        if (x0 < 0)            { wv0 = wx;        wv1 = 0.0f; }
        else if (x0 >= WW - 1) { wv0 = 0.0f;      wv1 = 1.0f - wx; }
        else                   { wv0 = 1.0f - wx; wv1 = wx; }
        float wr0 = (y0 >= 0)     ? (1.0f - wy) : 0.0f;
        float wr1 = (y0 + 1 < HH) ? wy          : 0.0f;
        int yc0 = min(max(y0, 0), HH - 1), yc1 = min(max(y0 + 1, 0), HH - 1);
        int o0 = yc0 * WW + xb, o1 = yc1 * WW + xb;
        #pragma unroll 4
        for (int j = 0; j < 32; ++j) {
            const float* p = planes + (size_t)j * HWV;
            tile[t][j] = wr0 * (p[o0] * wv0 + p[o0 + 1] * wv1)
                       + wr1 * (p[o1] * wv0 + p[o1 + 1] * wv1);
        }
        __syncthreads();
        for (int idx = t; idx < 8192; idx += 256) {
            int p = idx >> 5, k = idx & 31;
            outS[((size_t)b * NN + pidx[p]) * CC + c0 + k] = tile[p][k];
        }
    }
}

// ---------------------------------------------------------------------------
// K4: plain tile transpose outLp[b][r][c] -> outL[b][c][r].
__global__ __launch_bounds__(256) void transpose_k(const float* __restrict__ outLp,
                                                   float* __restrict__ outL) {
    __shared__ float tile[256][33];
    const int b = blockIdx.z, c0 = blockIdx.y * 32, r0 = blockIdx.x * 256;
    const int t = threadIdx.x;
    for (int idx = t; idx < 8192; idx += 256) {
        int p = idx >> 5, k = idx & 31;
        tile[p][k] = outLp[((size_t)b * NN + r0 + p) * CC + c0 + k];
    }
    __syncthreads();
    for (int idx = t; idx < 8192; idx += 256) {
        int cl = idx >> 8, col = idx & 255;
        outL[((size_t)b * CC + c0 + cl) * NN + r0 + col] = tile[col][cl];
    }
}

// ---------------------------------------------------------------------------
// K5 (fallback path only): coords + idx from the rank-order stash.
__global__ void emit_k(const u32* __restrict__ stash, float* __restrict__ outCoord,
                       float* __restrict__ outIdx) {
    int i = blockIdx.x * blockDim.x + threadIdx.x;
    u32 p = stash[i];
    u32 yi = p >> 8, xi = p & 255u;
    outCoord[(size_t)i * 2 + 0] = (float)yi / 255.0f;
    outCoord[(size_t)i * 2 + 1] = (float)xi / 255.0f;
    outIdx[i] = (float)p;
}

extern "C" void kernel_launch(void* const* d_in, const int* in_sizes, int n_in,
                              void* d_out, int out_size, void* d_ws, size_t ws_size,
                              hipStream_t stream) {
    const float* fm = (const float*)d_in[0];   // (8,256,256,256) f32
    const float* pm = (const float*)d_in[1];   // (8,1,256,256) f32
    const int*   em = (const int*)d_in[2];     // (8,256,256) i32
    const float* pc = (const float*)d_in[3];   // (8,4096,2) f32
    (void)in_sizes; (void)n_in; (void)out_size;

    float* out      = (float*)d_out;
    float* outL     = out;                         // local_feats (8,256,4096)
    float* outS     = out + (size_t)8388608;       // sampled     (8,4096,256)
    float* outCoord = out + (size_t)16777216;      // coords      (8,4096,2)
    float* outIdx   = out + (size_t)16842752;      // idx         (8,4096)

    const size_t need_ws = (size_t)40 * 1024 * 1024;
    bool ws_ok = ws_size >= need_ws;

    u64* keys; u32 *stash, *pixSorted, *pcSorted; float* outLp;
    if (ws_ok) {
        char* w = (char*)d_ws;
        keys      = (u64*)w;                                // 4 MB
        stash     = (u32*)(w + (size_t)4  * 1024 * 1024);   // (unused, DIRECT)
        pixSorted = (u32*)(w + (size_t)4300 * 1024);        // 128 KB
        pcSorted  = (u32*)(w + (size_t)4600 * 1024);        // 128 KB
        outLp     = (float*)(w + (size_t)5 * 1024 * 1024);  // 33.5 MB
    } else {
        keys      = (u64*)outS;
        stash     = (u32*)outIdx;
        pixSorted = (u32*)outCoord;
        pcSorted  = pixSorted + 32768;
        outLp     = outS;
    }

    hipLaunchKernelGGL(build_keys_k, dim3(2048), dim3(256), 0, stream, pm, em, keys);
    if (ws_ok) {
        hipLaunchKernelGGL((topk_sortpc_k<1>), dim3(16), dim3(1024), 0, stream,
                           keys, pc, stash, pixSorted, pcSorted, outCoord, outIdx);
        hipLaunchKernelGGL(staged_gather512_k, dim3(16, CC / CG, 8), dim3(512), 0, stream,
                           fm, pc, pixSorted, pcSorted, outLp, outS);
        hipLaunchKernelGGL(transpose_k, dim3(16, 8, 8), dim3(256), 0, stream, outLp, outL);
    } else {
        hipLaunchKernelGGL((topk_sortpc_k<0>), dim3(16), dim3(1024), 0, stream,
                           keys, pc, stash, pixSorted, pcSorted, outCoord, outIdx);
        hipLaunchKernelGGL((gather_k<1>), dim3(16, 8, 8), dim3(256), 0, stream,
                           fm, pc, pixSorted, pcSorted, outLp, outS);
        hipLaunchKernelGGL(transpose_k, dim3(16, 8, 8), dim3(256), 0, stream, outLp, outL);
        hipLaunchKernelGGL((gather_k<2>), dim3(16, 8, 8), dim3(256), 0, stream,
                           fm, pc, pixSorted, pcSorted, outS, outS);
        hipLaunchKernelGGL(emit_k, dim3(128), dim3(256), 0, stream, stash, outCoord, outIdx);
    }
}

// Round 13
// 325.214 us; speedup vs baseline: 4.5950x; 1.8263x over previous
//
#include <hip/hip_runtime.h>

#define CC 256
#define HH 256
#define WW 256
#define HWV 65536
#define NN 4096
#define SROWS 18     // staged rows: 16-row band + 1 above + 1 below
#define SSTRIDE 260  // padded LDS row stride (words)

using u64 = unsigned long long;
using u32 = unsigned int;

__device__ __forceinline__ u32 lbound(const u32* __restrict__ a, u32 n, u32 key) {
    u32 lo = 0, hi = n;
    while (lo < hi) { u32 mid = (lo + hi) >> 1; if (a[mid] < key) lo = mid + 1; else hi = mid; }
    return lo;
}

// ---------------------------------------------------------------------------
// K1: 48-bit sortable keys: (monotone(float) << 16) | (0xFFFF - pix).
__global__ void build_keys_k(const float* __restrict__ pm, const int* __restrict__ em,
                             u64* __restrict__ keys) {
    int i = blockIdx.x * blockDim.x + threadIdx.x;   // b*65536 + pix
    float f = (em[i] == 1) ? -fabsf(pm[i]) : -1e30f;
    u32 u = __float_as_uint(f);
    u32 k = (u & 0x80000000u) ? ~u : (u | 0x80000000u);
    u32 pix = (u32)i & 0xFFFFu;
    keys[i] = ((u64)k << 16) | (u64)(0xFFFFu - pix);
}

// ---------------------------------------------------------------------------
// K2: blocks 0-7 = per-batch exact top-k (4x12-bit radix select + desc bitonic
// + bitmap/popcount spatial emit). DIRECT=1 writes coords/idx here.
// blocks 8-15 = row counting-sort of point_coords.
template<int DIRECT>
__global__ __launch_bounds__(1024) void topk_sortpc_k(const u64* __restrict__ keys,
                                                      const float* __restrict__ pc,
                                                      u32* __restrict__ stash,
                                                      u32* __restrict__ pixSorted,
                                                      u32* __restrict__ pcSorted,
                                                      float* __restrict__ outCoord,
                                                      float* __restrict__ outIdx) {
    __shared__ u64 sel[NN];
    __shared__ u64 bm[1024];
    __shared__ u32 wp[1024];
    __shared__ u32 s_digit, s_rem, s_cnt;
    const int t = threadIdx.x;
    if (blockIdx.x < 8) {
        const int b = blockIdx.x;
        const u64* kb = keys + (size_t)b * HWV;
        u32* hist = (u32*)sel;
        u64 prefix = 0ULL;
        u32 remaining = NN;
        for (int r = 0; r < 4; ++r) {
            int shift = 36 - 12 * r;
            #pragma unroll
            for (int q = 0; q < 4; ++q) hist[t + q * 1024] = 0u;
            __syncthreads();
            for (int i = t; i < HWV; i += 1024) {
                u64 K = kb[i];
                if ((K >> (shift + 12)) == prefix)
                    atomicAdd(&hist[(u32)((K >> shift) & 0xFFFULL)], 1u);
            }
            __syncthreads();
            for (int off = 1; off < 4096; off <<= 1) {   // suffix sums
                u32 v[4];
                #pragma unroll
                for (int q = 0; q < 4; ++q) {
                    int i = t + q * 1024;
                    v[q] = hist[i];
                    if (i + off < 4096) v[q] += hist[i + off];
                }
                __syncthreads();
                #pragma unroll
                for (int q = 0; q < 4; ++q) hist[t + q * 1024] = v[q];
                __syncthreads();
            }
            #pragma unroll
            for (int q = 0; q < 4; ++q) {
                int d = t + q * 1024;
                u32 ge = hist[d];
                u32 gt = (d < 4095) ? hist[d + 1] : 0u;
                if (ge >= remaining && gt < remaining) { s_digit = (u32)d; s_rem = remaining - gt; }
            }
            __syncthreads();
            prefix = (prefix << 12) | (u64)s_digit;
            remaining = s_rem;
            __syncthreads();
        }
        if (t == 0) s_cnt = 0u;
        __syncthreads();
        for (int i = t; i < HWV; i += 1024) {
            u64 K = kb[i];
            if (K >= prefix) { u32 p = atomicAdd(&s_cnt, 1u); sel[p] = K; }
        }
        __syncthreads();
        for (int k = 2; k <= NN; k <<= 1) {           // bitonic desc
            for (int j = k >> 1; j > 0; j >>= 1) {
                for (int i = t; i < NN; i += 1024) {
                    int l = i ^ j;
                    if (l > i) {
                        u64 a = sel[i], c = sel[l];
                        bool asc = ((i & k) == 0);
                        if ((a < c) == asc) { sel[i] = c; sel[l] = a; }
                    }
                }
                __syncthreads();
            }
        }
        bm[t] = 0ULL;
        __syncthreads();
        #pragma unroll
        for (int q = 0; q < 4; ++q) {
            int r = t + q * 1024;
            u32 pix = 0xFFFFu - (u32)(sel[r] & 0xFFFFULL);
            if (DIRECT) {
                u32 yi = pix >> 8, xi = pix & 255u;
                outCoord[((size_t)b * NN + r) * 2 + 0] = (float)yi / 255.0f;
                outCoord[((size_t)b * NN + r) * 2 + 1] = (float)xi / 255.0f;
                outIdx[b * NN + r] = (float)pix;   // exact: pix < 2^24
            } else {
                stash[b * NN + r] = pix;
            }
            atomicOr(&bm[pix >> 6], 1ULL << (pix & 63));
        }
        __syncthreads();
        wp[t] = (u32)__popcll(bm[t]);
        __syncthreads();
        for (int off = 1; off < 1024; off <<= 1) {   // inclusive scan
            u32 v = wp[t];
            if (t >= off) v += wp[t - off];
            __syncthreads();
            wp[t] = v;
            __syncthreads();
        }
        #pragma unroll
        for (int q = 0; q < 4; ++q) {
            int r = t + q * 1024;
            u32 pix = 0xFFFFu - (u32)(sel[r] & 0xFFFFULL);
            int w = (int)(pix >> 6);
            u32 pos = wp[w] - (u32)__popcll(bm[w])
                    + (u32)__popcll(bm[w] & ((1ULL << (pix & 63)) - 1ULL));
            pixSorted[b * NN + pos] = (pix << 12) | (u32)r;
        }
    } else {
        const int b = blockIdx.x - 8;
        u32* cellArr = (u32*)sel;
        u32* hist256 = wp;
        u32* cnt     = (u32*)bm;
        if (t < 256) { hist256[t] = 0u; cnt[t] = 0u; }
        __syncthreads();
        for (int n = t; n < NN; n += 1024) {
            float gx = pc[((size_t)b * NN + n) * 2 + 0];
            float gy = pc[((size_t)b * NN + n) * 2 + 1];
            float fx = gx * 256.0f - 0.5f;
            float fy = gy * 256.0f - 0.5f;
            int x0 = (int)floorf(fx), y0 = (int)floorf(fy);
            int xc = min(max(x0, 0), 255), yc = min(max(y0, 0), 255);
            cellArr[n] = ((u32)(yc * 256 + xc) << 12) | (u32)n;
            atomicAdd(&hist256[yc], 1u);
        }
        __syncthreads();
        for (int off = 1; off < 256; off <<= 1) {
            u32 v = 0;
            if (t < 256) { v = hist256[t]; if (t >= off) v += hist256[t - off]; }
            __syncthreads();
            if (t < 256) hist256[t] = v;
            __syncthreads();
        }
        for (int n = t; n < NN; n += 1024) {
            u32 pk = cellArr[n];
            u32 yc = pk >> 20;
            u32 base = (yc > 0) ? hist256[yc - 1] : 0u;
            u32 pos = base + atomicAdd(&cnt[yc], 1u);
            pcSorted[b * NN + pos] = pk;
        }
    }
}

// ---------------------------------------------------------------------------
// Staging: 18-row band slice of one plane, coalesced float4, named registers.
#define STAGE_LOAD(plane) \
    { int idx, r, c4, gr; \
      idx = t;        r = idx >> 6; c4 = idx & 63; gr = min(max(rStart + r, 0), HH - 1); \
      g0 = *(const float4*)((plane) + gr * WW + c4 * 4); \
      idx = t + 256;  r = idx >> 6; c4 = idx & 63; gr = min(max(rStart + r, 0), HH - 1); \
      g1 = *(const float4*)((plane) + gr * WW + c4 * 4); \
      idx = t + 512;  r = idx >> 6; c4 = idx & 63; gr = min(max(rStart + r, 0), HH - 1); \
      g2 = *(const float4*)((plane) + gr * WW + c4 * 4); \
      idx = t + 768;  r = idx >> 6; c4 = idx & 63; gr = min(max(rStart + r, 0), HH - 1); \
      g3 = *(const float4*)((plane) + gr * WW + c4 * 4); \
      if (t < 128) { idx = t + 1024; r = idx >> 6; c4 = idx & 63; gr = min(max(rStart + r, 0), HH - 1); \
      g4 = *(const float4*)((plane) + gr * WW + c4 * 4); } }

#define STAGE_WRITE() \
    { int idx, r, c4; \
      idx = t;        r = idx >> 6; c4 = idx & 63; *(float4*)(sm + r * SSTRIDE + c4 * 4) = g0; \
      idx = t + 256;  r = idx >> 6; c4 = idx & 63; *(float4*)(sm + r * SSTRIDE + c4 * 4) = g1; \
      idx = t + 512;  r = idx >> 6; c4 = idx & 63; *(float4*)(sm + r * SSTRIDE + c4 * 4) = g2; \
      idx = t + 768;  r = idx >> 6; c4 = idx & 63; *(float4*)(sm + r * SSTRIDE + c4 * 4) = g3; \
      if (t < 128) { idx = t + 1024; r = idx >> 6; c4 = idx & 63; *(float4*)(sm + r * SSTRIDE + c4 * 4) = g4; } }

// ---------------------------------------------------------------------------
// K3: plane-major staged gather. Block = (band, 32-plane group, b). One plane
// staged at a time (single 18.7 KB LDS buffer, reg-prefetch of plane j+1
// issued before plane-j taps). Per plane, both point sets tap from LDS and
// results are written IMMEDIATELY in sorted-position layout (coalesced 1KB) —
// no loop-carried register arrays, no spill risk by construction.
__global__ __launch_bounds__(256) void plane_gather_k(const float* __restrict__ fm,
                                                      const float* __restrict__ pc,
                                                      const u32* __restrict__ pixSorted,
                                                      const u32* __restrict__ pcSorted,
                                                      float* __restrict__ outLc,
                                                      float* __restrict__ outSc) {
    __shared__ float sm[SROWS * SSTRIDE];
    const int band = blockIdx.x, c0 = blockIdx.y * 32, b = blockIdx.z;
    const int t = threadIdx.x;
    const int rStart = band * 16 - 1;
    const u32 keyLo = (u32)band << 24, keyHi = (u32)(band + 1) << 24;
    const u32* aL = pixSorted + b * NN;
    const u32* aS = pcSorted + b * NN;
    u32 loL = lbound(aL, NN, keyLo), cL = lbound(aL, NN, keyHi) - loL;
    u32 loS = lbound(aS, NN, keyLo), cS = lbound(aS, NN, keyHi) - loS;
    const float* planes = fm + ((size_t)b * CC + c0) * HWV;
    const float* pcb = pc + (size_t)b * NN * 2;

    // ---- decode 2 L chunks + 2 S chunks into named scalars (no arrays) ----
    int  Lo0 = 0, Lc2 = 0, Lr2 = 0;   float Lwc = 0, Lwr = 0, Lic = 0;
    int  Mo0 = 0, Mc2 = 0, Mr2 = 0;   float Mwc = 0, Mwr = 0, Mic = 0;
    int  So0 = 0, Sr1 = 0;            float Sv0 = 0, Sv1 = 0, Sw0 = 0, Sw1 = 0;
    int  To0 = 0, Tr1 = 0;            float Tv0 = 0, Tv1 = 0, Tw0 = 0, Tw1 = 0;
    {
        u32 jl = (u32)t;
        if (jl < cL) {
            u32 pix = aL[loL + jl] >> 12;
            int yi = (int)(pix >> 8), xi = (int)(pix & 255u);
            float cy = (float)yi / 255.0f, cx = (float)xi / 255.0f;   // exact ref pipeline
            int x = (int)(cx * 255.0f), y = (int)(cy * 255.0f);
            int x_min = max(x - 1, 0), wid = min(x + 2, WW) - x_min;
            int y_min = max(y - 1, 0), hgt = min(y + 2, HH) - y_min;
            Lo0 = (y_min - rStart) * SSTRIDE + x_min;
            Lc2 = (wid == 3) ? 2 : 0;  Lwc = (wid == 3) ? 1.0f : 0.0f;
            Lr2 = ((hgt == 3) ? 2 : 0) * SSTRIDE;  Lwr = (hgt == 3) ? 1.0f : 0.0f;
            Lic = 1.0f / (float)(wid * hgt);
        }
        jl = 256u + (u32)t;
        if (jl < cL) {
            u32 pix = aL[loL + jl] >> 12;
            int yi = (int)(pix >> 8), xi = (int)(pix & 255u);
            float cy = (float)yi / 255.0f, cx = (float)xi / 255.0f;
            int x = (int)(cx * 255.0f), y = (int)(cy * 255.0f);
            int x_min = max(x - 1, 0), wid = min(x + 2, WW) - x_min;
            int y_min = max(y - 1, 0), hgt = min(y + 2, HH) - y_min;
            Mo0 = (y_min - rStart) * SSTRIDE + x_min;
            Mc2 = (wid == 3) ? 2 : 0;  Mwc = (wid == 3) ? 1.0f : 0.0f;
            Mr2 = ((hgt == 3) ? 2 : 0) * SSTRIDE;  Mwr = (hgt == 3) ? 1.0f : 0.0f;
            Mic = 1.0f / (float)(wid * hgt);
        }
        u32 js = (u32)t;
        if (js < cS) {
            u32 sn = aS[loS + js] & 0xFFFu;
            float gx = pcb[2 * sn + 0], gy = pcb[2 * sn + 1];
            float fx = gx * 256.0f - 0.5f, fy = gy * 256.0f - 0.5f;   // exact
            float fx0 = floorf(fx), fy0 = floorf(fy);
            int x0 = (int)fx0, y0 = (int)fy0;
            float wx = fx - fx0, wy = fy - fy0;
            int xb = min(max(x0, 0), WW - 2);
            if (x0 < 0)            { Sv0 = wx;        Sv1 = 0.0f; }
            else if (x0 >= WW - 1) { Sv0 = 0.0f;      Sv1 = 1.0f - wx; }
            else                   { Sv0 = 1.0f - wx; Sv1 = wx; }
            Sw0 = (y0 >= 0)     ? (1.0f - wy) : 0.0f;
            Sw1 = (y0 + 1 < HH) ? wy          : 0.0f;
            int yc0 = min(max(y0, 0), HH - 1), yc1 = min(max(y0 + 1, 0), HH - 1);
            So0 = (yc0 - rStart) * SSTRIDE + xb;
            Sr1 = (yc1 - yc0) * SSTRIDE;
        }
        js = 256u + (u32)t;
        if (js < cS) {
            u32 sn = aS[loS + js] & 0xFFFu;
            float gx = pcb[2 * sn + 0], gy = pcb[2 * sn + 1];
            float fx = gx * 256.0f - 0.5f, fy = gy * 256.0f - 0.5f;
            float fx0 = floorf(fx), fy0 = floorf(fy);
            int x0 = (int)fx0, y0 = (int)fy0;
            float wx = fx - fx0, wy = fy - fy0;
            int xb = min(max(x0, 0), WW - 2);
            if (x0 < 0)            { Tv0 = wx;        Tv1 = 0.0f; }
            else if (x0 >= WW - 1) { Tv0 = 0.0f;      Tv1 = 1.0f - wx; }
            else                   { Tv0 = 1.0f - wx; Tv1 = wx; }
            Tw0 = (y0 >= 0)     ? (1.0f - wy) : 0.0f;
            Tw1 = (y0 + 1 < HH) ? wy          : 0.0f;
            int yc0 = min(max(y0, 0), HH - 1), yc1 = min(max(y0 + 1, 0), HH - 1);
            To0 = (yc0 - rStart) * SSTRIDE + xb;
            Tr1 = (yc1 - yc0) * SSTRIDE;
        }
    }

    float4 g0, g1, g2, g3, g4;
    STAGE_LOAD(planes)
    STAGE_WRITE()
    __syncthreads();

    #pragma unroll 1
    for (int j = 0; j < 32; ++j) {
        if (j + 1 < 32) { const float* np = planes + (size_t)(j + 1) * HWV; STAGE_LOAD(np) }
        // ---- taps from LDS, written immediately (sorted-position layout) ----
        float* oL = outLc + ((size_t)(b * CC + c0 + j)) * NN + loL;
        float* oS = outSc + ((size_t)(b * CC + c0 + j)) * NN + loS;
        if ((u32)t < cL) {
            float r0 = sm[Lo0] + sm[Lo0 + 1] + Lwc * sm[Lo0 + Lc2];
            float r1 = sm[Lo0 + SSTRIDE] + sm[Lo0 + SSTRIDE + 1] + Lwc * sm[Lo0 + SSTRIDE + Lc2];
            int o2 = Lo0 + Lr2;
            float r2 = sm[o2] + sm[o2 + 1] + Lwc * sm[o2 + Lc2];
            oL[t] = (r0 + r1 + Lwr * r2) * Lic;
        }
        if (256u + (u32)t < cL) {
            float r0 = sm[Mo0] + sm[Mo0 + 1] + Mwc * sm[Mo0 + Mc2];
            float r1 = sm[Mo0 + SSTRIDE] + sm[Mo0 + SSTRIDE + 1] + Mwc * sm[Mo0 + SSTRIDE + Mc2];
            int o2 = Mo0 + Mr2;
            float r2 = sm[o2] + sm[o2 + 1] + Mwc * sm[o2 + Mc2];
            oL[256 + t] = (r0 + r1 + Mwr * r2) * Mic;
        }
        if ((u32)t < cS) {
            oS[t] = Sw0 * (sm[So0] * Sv0 + sm[So0 + 1] * Sv1)
                  + Sw1 * (sm[So0 + Sr1] * Sv0 + sm[So0 + Sr1 + 1] * Sv1);
        }
        if (256u + (u32)t < cS) {
            oS[256 + t] = Tw0 * (sm[To0] * Tv0 + sm[To0 + 1] * Tv1)
                        + Tw1 * (sm[To0 + Tr1] * Tv0 + sm[To0 + Tr1 + 1] * Tv1);
        }
        __syncthreads();
        if (j + 1 < 32) { STAGE_WRITE() }
        __syncthreads();
    }

    // ---- overflow epilogue (cL/cS > 512: >16 sigma, never in practice) ----
    for (u32 jl = 512 + (u32)t; jl < cL; jl += 256) {
        u32 pix = aL[loL + jl] >> 12;
        int yi = (int)(pix >> 8), xi = (int)(pix & 255u);
        float cy = (float)yi / 255.0f, cx = (float)xi / 255.0f;
        int x = (int)(cx * 255.0f), y = (int)(cy * 255.0f);
        int x_min = max(x - 1, 0), x_max = min(x + 2, WW);
        int y_min = max(y - 1, 0), y_max = min(y + 2, HH);
        float ic = 1.0f / (float)((x_max - x_min) * (y_max - y_min));
        for (int j = 0; j < 32; ++j) {
            const float* p = planes + (size_t)j * HWV;
            float s = 0.0f;
            for (int yy = y_min; yy < y_max; ++yy)
                for (int xx = x_min; xx < x_max; ++xx) s += p[yy * WW + xx];
            outLc[((size_t)(b * CC + c0 + j)) * NN + loL + jl] = s * ic;
        }
    }
    for (u32 js = 512 + (u32)t; js < cS; js += 256) {
        u32 sn = aS[loS + js] & 0xFFFu;
        float gx = pcb[2 * sn + 0], gy = pcb[2 * sn + 1];
        float fx = gx * 256.0f - 0.5f, fy = gy * 256.0f - 0.5f;
        float fx0 = floorf(fx), fy0 = floorf(fy);
        int x0 = (int)fx0, y0 = (int)fy0;
        float wx = fx - fx0, wy = fy - fy0;
        int xb = min(max(x0, 0), WW - 2);
        float v0, v1, r0, r1;
        if (x0 < 0)            { v0 = wx;        v1 = 0.0f; }
        else if (x0 >= WW - 1) { v0 = 0.0f;      v1 = 1.0f - wx; }
        else                   { v0 = 1.0f - wx; v1 = wx; }
        r0 = (y0 >= 0)     ? (1.0f - wy) : 0.0f;
        r1 = (y0 + 1 < HH) ? wy          : 0.0f;
        int yc0 = min(max(y0, 0), HH - 1), yc1 = min(max(y0 + 1, 0), HH - 1);
        int o0 = yc0 * WW + xb, o1 = yc1 * WW + xb;
        for (int j = 0; j < 32; ++j) {
            const float* p = planes + (size_t)j * HWV;
            outSc[((size_t)(b * CC + c0 + j)) * NN + loS + js] =
                r0 * (p[o0] * v0 + p[o0 + 1] * v1) + r1 * (p[o1] * v0 + p[o1 + 1] * v1);
        }
    }
}

// ---------------------------------------------------------------------------
// K4: unpermute L: outL[b][c][rank[spos]] = outLc[b][c][spos] via LDS scatter.
__global__ __launch_bounds__(256) void unpermL_k(const float* __restrict__ outLc,
                                                 const u32* __restrict__ pixSorted,
                                                 float* __restrict__ outL) {
    __shared__ float row[NN];
    const int c = blockIdx.x, b = blockIdx.y;
    const int t = threadIdx.x;
    const float* in = outLc + ((size_t)(b * CC + c)) * NN;
    for (int j = t; j < NN; j += 256)
        row[pixSorted[b * NN + j] & 0xFFFu] = in[j];
    __syncthreads();
    float* o = outL + ((size_t)(b * CC + c)) * NN;
    for (int i = t; i < NN; i += 256) o[i] = row[i];
}

// ---------------------------------------------------------------------------
// K5: unpermute S: outS[b][n[spos]][c] = outSc[b][c][spos] (tile transpose).
__global__ __launch_bounds__(256) void unpermS_k(const float* __restrict__ outSc,
                                                 const u32* __restrict__ pcSorted,
                                                 float* __restrict__ outS) {
    __shared__ float tile[32][257];
    __shared__ u32 ns[256];
    const int j0 = blockIdx.x * 256, c0 = blockIdx.y * 32, b = blockIdx.z;
    const int t = threadIdx.x;
    ns[t] = pcSorted[b * NN + j0 + t] & 0xFFFu;
    for (int i = 0; i < 32; ++i)
        tile[i][t] = outSc[((size_t)(b * CC + c0 + i)) * NN + j0 + t];
    __syncthreads();
    for (int idx = t; idx < 8192; idx += 256) {
        int p = idx >> 5, k = idx & 31;
        outS[((size_t)b * NN + ns[p]) * CC + c0 + k] = tile[k][p];
    }
}

// ---------------------------------------------------------------------------
// Fallback kernels (no-ws path): round-10 proven merged/split gather.
template<int MODE>
__global__ __launch_bounds__(256, 4) void gather_k(const float* __restrict__ fm,
                                                   const float* __restrict__ pc,
                                                   const u32* __restrict__ pixSorted,
                                                   const u32* __restrict__ pcSorted,
                                                   float* __restrict__ outLp,
                                                   float* __restrict__ outS) {
    __shared__ float tile[256][33];
    __shared__ u32 pidx[256];
    const int b = blockIdx.z, j0 = blockIdx.x * 256, t = threadIdx.x;
    bool doL; int c0;
    if (MODE == 1) { doL = true; c0 = blockIdx.y * 32; }
    else { doL = false; c0 = blockIdx.y * 32; }
    const float* planes = fm + ((size_t)b * CC + c0) * HWV;
    if (doL) {
        u32 packed = pixSorted[b * NN + j0 + t];
        u32 pix = packed >> 12;
        pidx[t] = packed & 0xFFFu;
        int yi = (int)(pix >> 8), xi = (int)(pix & 255u);
        float cy = (float)yi / 255.0f, cx = (float)xi / 255.0f;
        int x = (int)(cx * 255.0f), y = (int)(cy * 255.0f);
        int x_min = max(x - 1, 0), x_max = min(x + 2, WW);
        int y_min = max(y - 1, 0), y_max = min(y + 2, HH);
        int base = min(x_min & ~3, WW - 8);
        float w8[8];
        #pragma unroll
        for (int i = 0; i < 8; ++i)
            w8[i] = (base + i >= x_min && base + i < x_max) ? 1.0f : 0.0f;
        float wr2 = (y_min + 2 < y_max) ? 1.0f : 0.0f;
        int o0 = y_min * WW + base, o1 = o0 + WW;
        int o2 = min(y_min + 2, HH - 1) * WW + base;
        float invc = 1.0f / (float)((x_max - x_min) * (y_max - y_min));
        #pragma unroll 2
        for (int j = 0; j < 32; ++j) {
            const float* p = planes + (size_t)j * HWV;
            float4 a0 = *(const float4*)(p + o0), b0 = *(const float4*)(p + o0 + 4);
            float4 a1 = *(const float4*)(p + o1), b1 = *(const float4*)(p + o1 + 4);
            float4 a2 = *(const float4*)(p + o2), b2 = *(const float4*)(p + o2 + 4);
            float s0 = a0.x * w8[0] + a0.y * w8[1] + a0.z * w8[2] + a0.w * w8[3]
                     + b0.x * w8[4] + b0.y * w8[5] + b0.z * w8[6] + b0.w * w8[7];
            float s1 = a1.x * w8[0] + a1.y * w8[1] + a1.z * w8[2] + a1.w * w8[3]
                     + b1.x * w8[4] + b1.y * w8[5] + b1.z * w8[6] + b1.w * w8[7];
            float s2 = a2.x * w8[0] + a2.y * w8[1] + a2.z * w8[2] + a2.w * w8[3]
                     + b2.x * w8[4] + b2.y * w8[5] + b2.z * w8[6] + b2.w * w8[7];
            tile[t][j] = (s0 + s1 + wr2 * s2) * invc;
        }
        __syncthreads();
        for (int idx = t; idx < 8192; idx += 256) {
            int p = idx >> 5, k = idx & 31;
            outLp[((size_t)b * NN + pidx[p]) * CC + c0 + k] = tile[p][k];
        }
    } else {
        int n = (int)(pcSorted[b * NN + j0 + t] & 0xFFFu);
        pidx[t] = (u32)n;
        float gx = pc[((size_t)b * NN + n) * 2 + 0];
        float gy = pc[((size_t)b * NN + n) * 2 + 1];
        float fx = gx * 256.0f - 0.5f, fy = gy * 256.0f - 0.5f;
        float fx0 = floorf(fx), fy0 = floorf(fy);
        int x0 = (int)fx0, y0 = (int)fy0;
        float wx = fx - fx0, wy = fy - fy0;
        int xb = min(max(x0, 0), WW - 2);
        float wv0, wv1;
        if (x0 < 0)            { wv0 = wx;        wv1 = 0.0f; }
        else if (x0 >= WW - 1) { wv0 = 0.0f;      wv1 = 1.0f - wx; }
        else                   { wv0 = 1.0f - wx; wv1 = wx; }
        float wr0 = (y0 >= 0)     ? (1.0f - wy) : 0.0f;
        float wr1 = (y0 + 1 < HH) ? wy          : 0.0f;
        int yc0 = min(max(y0, 0), HH - 1), yc1 = min(max(y0 + 1, 0), HH - 1);
        int o0 = yc0 * WW + xb, o1 = yc1 * WW + xb;
        #pragma unroll 4
        for (int j = 0; j < 32; ++j) {
            const float* p = planes + (size_t)j * HWV;
            tile[t][j] = wr0 * (p[o0] * wv0 + p[o0 + 1] * wv1)
                       + wr1 * (p[o1] * wv0 + p[o1 + 1] * wv1);
        }
        __syncthreads();
        for (int idx = t; idx < 8192; idx += 256) {
            int p = idx >> 5, k = idx & 31;
            outS[((size_t)b * NN + pidx[p]) * CC + c0 + k] = tile[p][k];
        }
    }
}

__global__ __launch_bounds__(256) void transpose_k(const float* __restrict__ outLp,
                                                   float* __restrict__ outL) {
    __shared__ float tile[256][33];
    const int b = blockIdx.z, c0 = blockIdx.y * 32, r0 = blockIdx.x * 256;
    const int t = threadIdx.x;
    for (int idx = t; idx < 8192; idx += 256) {
        int p = idx >> 5, k = idx & 31;
        tile[p][k] = outLp[((size_t)b * NN + r0 + p) * CC + c0 + k];
    }
    __syncthreads();
    for (int idx = t; idx < 8192; idx += 256) {
        int cl = idx >> 8, col = idx & 255;
        outL[((size_t)b * CC + c0 + cl) * NN + r0 + col] = tile[col][cl];
    }
}

__global__ void emit_k(const u32* __restrict__ stash, float* __restrict__ outCoord,
                       float* __restrict__ outIdx) {
    int i = blockIdx.x * blockDim.x + threadIdx.x;
    u32 p = stash[i];
    u32 yi = p >> 8, xi = p & 255u;
    outCoord[(size_t)i * 2 + 0] = (float)yi / 255.0f;
    outCoord[(size_t)i * 2 + 1] = (float)xi / 255.0f;
    outIdx[i] = (float)p;
}

extern "C" void kernel_launch(void* const* d_in, const int* in_sizes, int n_in,
                              void* d_out, int out_size, void* d_ws, size_t ws_size,
                              hipStream_t stream) {
    const float* fm = (const float*)d_in[0];   // (8,256,256,256) f32
    const float* pm = (const float*)d_in[1];   // (8,1,256,256) f32
    const int*   em = (const int*)d_in[2];     // (8,256,256) i32
    const float* pc = (const float*)d_in[3];   // (8,4096,2) f32
    (void)in_sizes; (void)n_in; (void)out_size;

    float* out      = (float*)d_out;
    float* outL     = out;                         // local_feats (8,256,4096)
    float* outS     = out + (size_t)8388608;       // sampled     (8,4096,256)
    float* outCoord = out + (size_t)16777216;      // coords      (8,4096,2)
    float* outIdx   = out + (size_t)16842752;      // idx         (8,4096)

    const size_t need_ws = (size_t)80 * 1024 * 1024;
    bool ws_ok = ws_size >= need_ws;

    if (ws_ok) {
        char* w = (char*)d_ws;
        u64* keys      = (u64*)w;                                // 4 MB
        u32* pixSorted = (u32*)(w + (size_t)4300 * 1024);        // 128 KB
        u32* pcSorted  = (u32*)(w + (size_t)4600 * 1024);        // 128 KB
        float* outLc   = (float*)(w + (size_t)5  * 1024 * 1024); // 33.5 MB
        float* outSc   = (float*)(w + (size_t)40 * 1024 * 1024); // 33.5 MB

        hipLaunchKernelGGL(build_keys_k, dim3(2048), dim3(256), 0, stream, pm, em, keys);
        hipLaunchKernelGGL((topk_sortpc_k<1>), dim3(16), dim3(1024), 0, stream,
                           keys, pc, (u32*)nullptr, pixSorted, pcSorted, outCoord, outIdx);
        hipLaunchKernelGGL(plane_gather_k, dim3(16, 8, 8), dim3(256), 0, stream,
                           fm, pc, pixSorted, pcSorted, outLc, outSc);
        hipLaunchKernelGGL(unpermL_k, dim3(256, 8), dim3(256), 0, stream,
                           outLc, pixSorted, outL);
        hipLaunchKernelGGL(unpermS_k, dim3(16, 8, 8), dim3(256), 0, stream,
                           outSc, pcSorted, outS);
    } else {
        // alias scheme: keys/outLp in seg1 (final writer = gather<2>),
        // pixSorted/pcSorted in seg2 (final writer = emit), stash in seg3.
        u64* keys      = (u64*)outS;
        u32* stash     = (u32*)outIdx;
        u32* pixSorted = (u32*)outCoord;
        u32* pcSorted  = pixSorted + 32768;
        float* outLp   = outS;

        hipLaunchKernelGGL(build_keys_k, dim3(2048), dim3(256), 0, stream, pm, em, keys);
        hipLaunchKernelGGL((topk_sortpc_k<0>), dim3(16), dim3(1024), 0, stream,
                           keys, pc, stash, pixSorted, pcSorted, outCoord, outIdx);
        hipLaunchKernelGGL((gather_k<1>), dim3(16, 8, 8), dim3(256), 0, stream,
                           fm, pc, pixSorted, pcSorted, outLp, outS);
        hipLaunchKernelGGL(transpose_k, dim3(16, 8, 8), dim3(256), 0, stream, outLp, outL);
        hipLaunchKernelGGL((gather_k<2>), dim3(16, 8, 8), dim3(256), 0, stream,
                           fm, pc, pixSorted, pcSorted, outS, outS);
        hipLaunchKernelGGL(emit_k, dim3(128), dim3(256), 0, stream, stash, outCoord, outIdx);
    }
}